// Round 6
// baseline (239.334 us; speedup 1.0000x reference)
//
#include <hip/hip_runtime.h>
#include <stdint.h>

typedef unsigned short u16;
typedef __bf16 bf16x8 __attribute__((ext_vector_type(8)));
typedef u16 u16x8 __attribute__((ext_vector_type(8)));
typedef u16 u16x4 __attribute__((ext_vector_type(4)));
typedef float f32x4 __attribute__((ext_vector_type(4)));
typedef float f32x16 __attribute__((ext_vector_type(16)));

#define SEQ 4096
#define CD 1024
#define NH 16
#define DHD 64

__device__ __forceinline__ u16 f2bf(float f) {
  union { float f; unsigned u; } v; v.f = f;
  unsigned r = v.u + 0x7fffu + ((v.u >> 16) & 1u);
  return (u16)(r >> 16);
}
__device__ __forceinline__ unsigned fbits(float f) {
  union { float f; unsigned u; } v; v.f = f; return v.u;
}

__device__ __forceinline__ void load_lds16(const u16* g, u16* l) {
  __builtin_amdgcn_global_load_lds((const __attribute__((address_space(1))) void*)g,
                                   (__attribute__((address_space(3))) void*)l, 16, 0, 0);
}

// ---------------- convert fp32 -> bf16 (single dispatch) ----------------
__global__ __launch_bounds__(256) void cvt_all(const float* __restrict__ x, const float* __restrict__ Wq,
                                               const float* __restrict__ Wk, const float* __restrict__ Wv,
                                               const float* __restrict__ Wp,
                                               u16* __restrict__ xb, u16* __restrict__ Wb, u16* __restrict__ Wpb) {
  int b = blockIdx.x;
  const float* src; u16* dst; int base;
  if (b < 2048)      { src = x;  dst = xb;             base = b; }
  else if (b < 2560) { src = Wq; dst = Wb;             base = b - 2048; }
  else if (b < 3072) { src = Wk; dst = Wb + CD * CD;   base = b - 2560; }
  else if (b < 3584) { src = Wv; dst = Wb + 2*CD*CD;   base = b - 3072; }
  else               { src = Wp; dst = Wpb;            base = b - 3584; }
  int i = (base * 256 + (int)threadIdx.x) * 8;
  float4 a = *(const float4*)(src + i);
  float4 c = *(const float4*)(src + i + 4);
  u16x8 o;
  o[0] = f2bf(a.x); o[1] = f2bf(a.y); o[2] = f2bf(a.z); o[3] = f2bf(a.w);
  o[4] = f2bf(c.x); o[5] = f2bf(c.y); o[6] = f2bf(c.z); o[7] = f2bf(c.w);
  *(u16x8*)(dst + i) = o;
}

// ---------------- GEMM core: out = (A * Bw^T + bias) * oscale ----------------
// A [M x 1024], Bw [N x 1024] (dot of rows). MODE 0: bf16 out[row*CD+col], bias[col].
// MODE 2: f32 out[row*CD+col], bias[col]. MODE 3: bf16 out[row*SEQ+col], bias[row] (V^T path).
template<int MODE>
__device__ __forceinline__ void gemm_core(const u16* __restrict__ A, const u16* __restrict__ Bw,
                                          const float* __restrict__ bias, void* __restrict__ outp,
                                          float oscale, int rowA0, int rowB0) {
  constexpr int K = CD;
  __shared__ u16 As[128 * 32];
  __shared__ u16 Bs[128 * 32];
  const int tid = threadIdx.x;
  const int w = tid >> 6, L = tid & 63, q = L >> 4, ln = L & 15;
  const int wr = (w >> 1) * 64, wc = (w & 1) * 64;
  f32x4 acc[4][4] = {};
  for (int k0 = 0; k0 < K; k0 += 32) {
#pragma unroll
    for (int pass = 0; pass < 2; ++pass) {
      int off = pass * 4096 + tid * 16;
      int row = off >> 6;
      int cole = (off & 63) >> 1;
      load_lds16(A + (size_t)(rowA0 + row) * K + k0 + cole, As + pass * 2048 + w * 512);
      load_lds16(Bw + (size_t)(rowB0 + row) * K + k0 + cole, Bs + pass * 2048 + w * 512);
    }
    __syncthreads();
    bf16x8 af[4], bg[4];
#pragma unroll
    for (int i = 0; i < 4; ++i) af[i] = *(const bf16x8*)(As + (wr + i * 16 + ln) * 32 + q * 8);
#pragma unroll
    for (int i = 0; i < 4; ++i) bg[i] = *(const bf16x8*)(Bs + (wc + i * 16 + ln) * 32 + q * 8);
#pragma unroll
    for (int i = 0; i < 4; ++i)
#pragma unroll
      for (int j = 0; j < 4; ++j)
        acc[i][j] = __builtin_amdgcn_mfma_f32_16x16x32_bf16(af[i], bg[j], acc[i][j], 0, 0, 0);
    __syncthreads();
  }
#pragma unroll
  for (int i = 0; i < 4; ++i) {
#pragma unroll
    for (int j = 0; j < 4; ++j) {
      int col = rowB0 + wc + j * 16 + ln;
      float bb = (MODE == 3) ? 0.f : bias[col];
#pragma unroll
      for (int r = 0; r < 4; ++r) {
        int row = rowA0 + wr + i * 16 + q * 4 + r;
        float v = (MODE == 3) ? (acc[i][j][r] + bias[row]) * oscale
                              : (acc[i][j][r] + bb) * oscale;
        if (MODE == 0)      ((u16*)outp)[(size_t)row * CD + col] = f2bf(v);
        else if (MODE == 2) ((float*)outp)[(size_t)row * CD + col] = v;
        else                ((u16*)outp)[(size_t)row * SEQ + col] = f2bf(v);
      }
    }
  }
}

// fused QKV: 1D grid of 768 blocks. V^T computed directly as Wv·x^T (coalesced row-major store).
__global__ __launch_bounds__(256) void gemm_qkv(const u16* __restrict__ xb, const u16* __restrict__ Wb,
                                                const float* __restrict__ bq, const float* __restrict__ bk,
                                                const float* __restrict__ bv, u16* __restrict__ Qb,
                                                u16* __restrict__ Kb, u16* __restrict__ VTb) {
  int b = blockIdx.x;
  if (b < 256) {
    gemm_core<0>(xb, Wb, bq, Qb, 0.03125f, (b >> 3) * 128, (b & 7) * 128);   // Q (softmax scale folded)
  } else if (b < 512) {
    b -= 256;
    gemm_core<0>(xb, Wb + CD * CD, bk, Kb, 1.0f, (b >> 3) * 128, (b & 7) * 128);  // K
  } else {
    b -= 512;  // V^T: A = Wv [1024x1024], B = x [4096x1024], out [1024 x 4096], bias per-row(d)
    gemm_core<3>(Wb + 2 * CD * CD, xb, bv, VTb, 1.0f, (b >> 5) * 128, (b & 31) * 128);
  }
}

__global__ __launch_bounds__(256) void gemm_proj(const u16* __restrict__ A, const u16* __restrict__ Bw,
                                                 const float* __restrict__ bias, float* __restrict__ out) {
  gemm_core<2>(A, Bw, bias, out, 1.0f, blockIdx.y * 128, blockIdx.x * 128);
}

// ---------------- flash attention (causal), 64 q-rows/block, 2 waves, S^T form ----------------
// VERBATIM round-4 kernel (passed @ 90 µs). Q pre-scaled by C^-0.5. No running max.
// S^T = K·Q^T; lane owns one q-column; P^T -> PV B-frags in registers
// (v_perm_b32 pack + v_permlane32_swap_b32); O^T = V^T·P^T. Double-buffered LDS, one barrier/tile.
__global__ __launch_bounds__(128) void attn_kernel(const u16* __restrict__ Q, const u16* __restrict__ Kg,
                                                   const u16* __restrict__ VTg, u16* __restrict__ O) {
  __shared__ u16 Ks[2][64 * 72];
  __shared__ u16 Vt[2][64 * 72];
  const int tid = threadIdx.x, w = tid >> 6, L = tid & 63;
  const int ln = L & 31, hh = L >> 5;
  const int b = blockIdx.x;
  const int qt = (SEQ / 64 - 1) - (b >> 4);  // descending length (LPT)
  const int h = b & 15;
  const int colH = h * DHD;
  const int qrow0 = qt * 64 + w * 32;
  // Q B-frags (k = kk*16 + hh*8 + j over d=0..63), hoisted
  bf16x8 qf[4];
#pragma unroll
  for (int kk = 0; kk < 4; ++kk)
    qf[kk] = *(const bf16x8*)(Q + (size_t)(qrow0 + ln) * CD + colH + kk * 16 + hh * 8);
  f32x16 oa[2] = {};
  float lsum = 0.f;
  // staging map: p-th chunk -> row p*16 + (tid>>3), x = tid&7 (8 consecutive lanes = 128B line)
  const int srow = tid >> 3, sx = tid & 7;
  u16x8 kr[4], vr[4];
#pragma unroll
  for (int p = 0; p < 4; ++p) {
    kr[p] = *(const u16x8*)(Kg + (size_t)(p * 16 + srow) * CD + colH + sx * 8);
    vr[p] = *(const u16x8*)(VTg + (size_t)(colH + p * 16 + srow) * SEQ + sx * 8);
  }
  for (int jt = 0; jt <= qt; ++jt) {
    const int buf = jt & 1;
    u16* KsB = Ks[buf];
    u16* VtB = Vt[buf];
#pragma unroll
    for (int p = 0; p < 4; ++p) {
      *(u16x8*)(KsB + (p * 16 + srow) * 72 + sx * 8) = kr[p];
      *(u16x8*)(VtB + (p * 16 + srow) * 72 + sx * 8) = vr[p];
    }
    __syncthreads();  // single barrier per tile (double-buffered: no WAR across bufs)
    if (jt < qt) {    // prefetch next tile; latency hidden behind compute
      const size_t kb2 = (size_t)(jt + 1) * 64;
#pragma unroll
      for (int p = 0; p < 4; ++p) {
        kr[p] = *(const u16x8*)(Kg + (kb2 + p * 16 + srow) * CD + colH + sx * 8);
        vr[p] = *(const u16x8*)(VTg + (size_t)(colH + p * 16 + srow) * SEQ + kb2 + sx * 8);
      }
    }
    const bool diag = (jt == qt);
    unsigned pk[16];
    // ---- S^T = K Q^T, mask, exp, pack ----
#pragma unroll
    for (int nt = 0; nt < 2; ++nt) {
      f32x16 a = {};
#pragma unroll
      for (int kk = 0; kk < 4; ++kk) {
        bf16x8 kf = *(const bf16x8*)(KsB + (nt * 32 + ln) * 72 + kk * 16 + hh * 8);
        a = __builtin_amdgcn_mfma_f32_32x32x16_bf16(kf, qf[kk], a, 0, 0, 0);
      }
#pragma unroll
      for (int r = 0; r < 16; ++r) {
        float sv = a[r];
        if (diag) {
          const int key_l = nt * 32 + (r & 3) + 8 * (r >> 2) + 4 * hh;
          if (key_l > w * 32 + ln) sv = -1e30f;
        }
        float p = __expf(sv);
        lsum += p;
        a[r] = p;
      }
      // pack fp32 pairs -> bf16 (truncation): pk holds keys (2i, 2i+1) of this lane's set
#pragma unroll
      for (int i = 0; i < 8; ++i)
        pk[nt * 8 + i] = __builtin_amdgcn_perm(fbits(a[2 * i + 1]), fbits(a[2 * i]), 0x07060302);
    }
    // ---- exchange complementary key quads across half-wave: builds PV B-frags in-place ----
#pragma unroll
    for (int b0 = 0; b0 < 16; b0 += 4) {
      asm("v_permlane32_swap_b32 %0, %1" : "+v"(pk[b0 + 0]), "+v"(pk[b0 + 2]));
      asm("v_permlane32_swap_b32 %0, %1" : "+v"(pk[b0 + 1]), "+v"(pk[b0 + 3]));
    }
    // ---- O^T += V^T P^T ----
#pragma unroll
    for (int g = 0; g < 2; ++g)
#pragma unroll
      for (int s = 0; s < 4; ++s) {
        bf16x8 vf = *(const bf16x8*)(VtB + (g * 32 + ln) * 72 + s * 16 + hh * 8);
        union { unsigned u[4]; bf16x8 v; } pf;
        pf.u[0] = pk[s * 4 + 0]; pf.u[1] = pk[s * 4 + 1];
        pf.u[2] = pk[s * 4 + 2]; pf.u[3] = pk[s * 4 + 3];
        oa[g] = __builtin_amdgcn_mfma_f32_32x32x16_bf16(vf, pf.v, oa[g], 0, 0, 0);
      }
  }
  // l total for this lane's q: own half + partner half
  lsum += __shfl_xor(lsum, 32, 64);
  const float inv = 1.0f / lsum;
  // O^T epilogue: lane ln owns q-row qrow0+ln; d = colH + g*32 + (r&3)+8*(r>>2)+4*hh
#pragma unroll
  for (int g = 0; g < 2; ++g)
#pragma unroll
    for (int rg = 0; rg < 4; ++rg) {
      u16x4 ov;
#pragma unroll
      for (int i = 0; i < 4; ++i) ov[i] = f2bf(oa[g][rg * 4 + i] * inv);
      *(u16x4*)(O + (size_t)(qrow0 + ln) * CD + colH + g * 32 + 8 * rg + 4 * hh) = ov;
    }
}

extern "C" void kernel_launch(void* const* d_in, const int* in_sizes, int n_in,
                              void* d_out, int out_size, void* d_ws, size_t ws_size,
                              hipStream_t stream) {
  const float* x  = (const float*)d_in[0];
  const float* Wq = (const float*)d_in[1];
  const float* bq = (const float*)d_in[2];
  const float* Wk = (const float*)d_in[3];
  const float* bk = (const float*)d_in[4];
  const float* Wv = (const float*)d_in[5];
  const float* bv = (const float*)d_in[6];
  const float* Wp = (const float*)d_in[7];
  const float* bp = (const float*)d_in[8];

  char* ws = (char*)d_ws;
  u16* xb  = (u16*)(ws);                        // 8 MiB : x bf16
  u16* Wb  = (u16*)(ws + (8u << 20));           // 6 MiB : Wq,Wk,Wv bf16
  u16* Wpb = (u16*)(ws + (14u << 20));          // 2 MiB : Wp bf16
  u16* Qb  = (u16*)(ws + (16u << 20));          // 8 MiB : Q (pre-scaled by 1/32)
  u16* Kb  = (u16*)(ws + (24u << 20));          // 8 MiB
  u16* VTb = (u16*)(ws + (32u << 20));          // 8 MiB : V transposed [1024][4096]
  u16* Ab  = (u16*)(ws + (40u << 20));          // 8 MiB : attention output bf16

  cvt_all<<<4096, 256, 0, stream>>>(x, Wq, Wk, Wv, Wp, xb, Wb, Wpb);
  gemm_qkv<<<768, 256, 0, stream>>>(xb, Wb, bq, bk, bv, Qb, Kb, VTb);
  attn_kernel<<<(SEQ / 64) * NH, 128, 0, stream>>>(Qb, Kb, VTb, Ab);
  gemm_proj<<<dim3(CD / 128, SEQ / 128), 256, 0, stream>>>(Ab, Wpb, bp, (float*)d_out);
}